// Round 5
// baseline (166.510 us; speedup 1.0000x reference)
//
#include <hip/hip_runtime.h>

// GRU (B=4096, T=512, I=1, H=32) + FC(32->12), fused, dot2-f16 matvec,
// TWO batch elements per lane.
//
// Layout: lane = hidden unit j for batch pair (b0, b1) = (blk*16+g, +8).
// 32 lanes per group, 8 groups per 256-thread block -> 16 batch/block,
// 256 blocks = 1024 waves = 1 wave/SIMD. Each lane runs two independent
// GRU chains with a SHARED 48-VGPR f16x2 weight file: while chain A waits
// on its LDS h round-trip / exp latency, chain B's dot2s issue (round-4
// showed ~200 idle cyc/step from the serial h-exchange with nothing to
// overlap). waves_per_eu(1,2) gives a >=256 VGPR budget - no AGPR demotion.
//
// exp scale folding: sigmoid gates' weights pre-scaled by -log2(e), n-gate
// by +2*log2(e), so activations use raw v_exp_f32 (2^x) with no preamble.

namespace {

typedef _Float16 f16x2 __attribute__((ext_vector_type(2)));
typedef _Float16 f16x8 __attribute__((ext_vector_type(8)));

constexpr int kH = 32;
constexpr int kT = 512;
constexpr int kO = 12;
constexpr int kGPB = 16;  // batch elements per block (8 groups x 2)

__device__ __forceinline__ float fast_exp2(float a) {
#if __has_builtin(__builtin_amdgcn_exp2f)
    return __builtin_amdgcn_exp2f(a);
#else
    return exp2f(a);
#endif
}
__device__ __forceinline__ float fast_rcp(float a) {
#if __has_builtin(__builtin_amdgcn_rcpf)
    return __builtin_amdgcn_rcpf(a);
#else
    return 1.0f / a;
#endif
}

__device__ __forceinline__ float dot2(f16x2 a, f16x2 b, float c) {
#if __has_builtin(__builtin_amdgcn_fdot2)
    return __builtin_amdgcn_fdot2(a, b, c, false);
#else
    return fmaf((float)a[1], (float)b[1], fmaf((float)a[0], (float)b[0], c));
#endif
}

union V8 {
    f16x8 v;
    f16x2 p[4];
};

__global__ __launch_bounds__(256)
__attribute__((amdgpu_waves_per_eu(1, 2)))
void gru_fused(
    const float* __restrict__ x,      // [4096, 512, 1]
    const float* __restrict__ w_ih,   // [96, 1]
    const float* __restrict__ w_hh,   // [96, 32]
    const float* __restrict__ b_ih,   // [96]
    const float* __restrict__ b_hh,   // [96]
    const float* __restrict__ fc_w,   // [12, 32]
    const float* __restrict__ fc_b,   // [12]
    float* __restrict__ out)          // [4096, 12]
{
    __shared__ _Float16 hbuf[kGPB][kH];   // f16 h for the matvec
    __shared__ float    hfin[kGPB][kH];   // f32 final h for the FC epilogue

    const int tid = threadIdx.x;
    const int g   = tid >> 5;             // group 0..7
    const int j   = tid & 31;             // hidden unit owned by this lane
    const int b0  = blockIdx.x * kGPB + g;
    const int b1  = b0 + 8;
    const int g1  = g + 8;

    const float kL2E = 1.4426950408889634f;   // log2(e)

    // ---- shared per-lane weights: rows j (r), j+32 (z), j+64 (n),
    //      f16x2-packed, exp-scale folded: r,z by -log2e ; n by +2*log2e ----
    f16x2 wr[kH / 2], wz[kH / 2], wn[kH / 2];
    {
        const float* Wr = w_hh + (size_t)j * kH;
        const float* Wz = w_hh + (size_t)(j + kH) * kH;
        const float* Wn = w_hh + (size_t)(j + 2 * kH) * kH;
#pragma unroll
        for (int m = 0; m < kH / 2; ++m) {
            wr[m] = f16x2{(_Float16)(-kL2E * Wr[2 * m]),
                          (_Float16)(-kL2E * Wr[2 * m + 1])};
            wz[m] = f16x2{(_Float16)(-kL2E * Wz[2 * m]),
                          (_Float16)(-kL2E * Wz[2 * m + 1])};
            wn[m] = f16x2{(_Float16)(2.0f * kL2E * Wn[2 * m]),
                          (_Float16)(2.0f * kL2E * Wn[2 * m + 1])};
        }
    }

    // input-side constants (I == 1), same scale folding
    const float wih_r = -kL2E * w_ih[j];
    const float wih_z = -kL2E * w_ih[j + kH];
    const float wih_n = 2.0f * kL2E * w_ih[j + 2 * kH];
    const float bias_r = -kL2E * (b_ih[j] + b_hh[j]);
    const float bias_z = -kL2E * (b_ih[j + kH] + b_hh[j + kH]);
    const float bi_n = 2.0f * kL2E * b_ih[j + 2 * kH];
    const float bh_n = 2.0f * kL2E * b_hh[j + 2 * kH];

    float h0 = 0.0f, h1 = 0.0f;
    hbuf[g][j]  = (_Float16)0.0f;   // same-wave writes precede all reads
    hbuf[g1][j] = (_Float16)0.0f;

    const float4* xr0 = reinterpret_cast<const float4*>(x + (size_t)b0 * kT);
    const float4* xr1 = reinterpret_cast<const float4*>(x + (size_t)b1 * kT);
    const f16x8*  hbA = reinterpret_cast<const f16x8*>(&hbuf[g][0]);
    const f16x8*  hbB = reinterpret_cast<const f16x8*>(&hbuf[g1][0]);

    float4 xv0 = xr0[0];
    float4 xv1 = xr1[0];

    for (int t0 = 0; t0 < kT; t0 += 4) {
        const int nq = (t0 + 4 < kT) ? (t0 >> 2) + 1 : (t0 >> 2);
        float4 xn0 = xr0[nq];
        float4 xn1 = xr1[nq];

#pragma unroll
        for (int tt = 0; tt < 4; ++tt) {
            const float xt0 = (tt == 0) ? xv0.x : (tt == 1) ? xv0.y
                            : (tt == 2) ? xv0.z : xv0.w;
            const float xt1 = (tt == 0) ? xv1.x : (tt == 1) ? xv1.y
                            : (tt == 2) ? xv1.z : xv1.w;

            // ---- load both h vectors (independent LDS reads) ----
            V8 a0, a1, a2, a3, c0, c1, c2, c3;
            a0.v = hbA[0]; a1.v = hbA[1]; a2.v = hbA[2]; a3.v = hbA[3];
            c0.v = hbB[0]; c1.v = hbB[1]; c2.v = hbB[2]; c3.v = hbB[3];
            f16x2 hpA[kH / 2], hpB[kH / 2];
#pragma unroll
            for (int p = 0; p < 4; ++p) {
                hpA[0 + p]  = a0.p[p];  hpA[4 + p]  = a1.p[p];
                hpA[8 + p]  = a2.p[p];  hpA[12 + p] = a3.p[p];
                hpB[0 + p]  = c0.p[p];  hpB[4 + p]  = c1.p[p];
                hpB[8 + p]  = c2.p[p];  hpB[12 + p] = c3.p[p];
            }

            // ---- two independent matvec+gate chains ----
            float ar0 = fmaf(xt0, wih_r, bias_r);
            float az0 = fmaf(xt0, wih_z, bias_z);
            float an0 = bh_n;
            const float inn0 = fmaf(xt0, wih_n, bi_n);
            float ar1 = fmaf(xt1, wih_r, bias_r);
            float az1 = fmaf(xt1, wih_z, bias_z);
            float an1 = bh_n;
            const float inn1 = fmaf(xt1, wih_n, bi_n);

#pragma unroll
            for (int m = 0; m < kH / 2; ++m) {
                ar0 = dot2(wr[m], hpA[m], ar0);
                az0 = dot2(wz[m], hpA[m], az0);
                an0 = dot2(wn[m], hpA[m], an0);
                ar1 = dot2(wr[m], hpB[m], ar1);
                az1 = dot2(wz[m], hpB[m], az1);
                an1 = dot2(wn[m], hpB[m], an1);
            }

            const float r0 = fast_rcp(1.0f + fast_exp2(ar0));
            const float z0 = fast_rcp(1.0f + fast_exp2(az0));
            const float t0_ = fmaf(r0, an0, inn0);
            const float n0 = fmaf(-2.0f, fast_rcp(1.0f + fast_exp2(t0_)), 1.0f);
            h0 = fmaf(z0, h0 - n0, n0);

            const float r1 = fast_rcp(1.0f + fast_exp2(ar1));
            const float z1 = fast_rcp(1.0f + fast_exp2(az1));
            const float t1_ = fmaf(r1, an1, inn1);
            const float n1 = fmaf(-2.0f, fast_rcp(1.0f + fast_exp2(t1_)), 1.0f);
            h1 = fmaf(z1, h1 - n1, n1);

            hbuf[g][j]  = (_Float16)h0;   // publish for next step (same wave)
            hbuf[g1][j] = (_Float16)h1;
        }
        xv0 = xn0;
        xv1 = xn1;
    }

    // ---- FC epilogue: out[b][o] = fc_w[o] . h + fc_b[o] ----
    hfin[g][j]  = h0;
    hfin[g1][j] = h1;
    if (j < kO) {
        const float* fw = fc_w + (size_t)j * kH;
        float acc0 = fc_b[j];
        float acc1 = fc_b[j];
#pragma unroll
        for (int k = 0; k < kH; ++k) {
            acc0 = fmaf(fw[k], hfin[g][k], acc0);
            acc1 = fmaf(fw[k], hfin[g1][k], acc1);
        }
        out[(size_t)b0 * kO + j] = acc0;
        out[(size_t)b1 * kO + j] = acc1;
    }
}

}  // namespace

extern "C" void kernel_launch(void* const* d_in, const int* in_sizes, int n_in,
                              void* d_out, int out_size, void* d_ws, size_t ws_size,
                              hipStream_t stream) {
    const float* x    = (const float*)d_in[0];
    const float* w_ih = (const float*)d_in[1];
    const float* w_hh = (const float*)d_in[2];
    const float* b_ih = (const float*)d_in[3];
    const float* b_hh = (const float*)d_in[4];
    const float* fc_w = (const float*)d_in[5];
    const float* fc_b = (const float*)d_in[6];
    float* out = (float*)d_out;

    dim3 grid(4096 / kGPB);   // 256 blocks, 4 waves each -> 1024 waves
    dim3 block(256);
    gru_fused<<<grid, block, 0, stream>>>(x, w_ih, w_hh, b_ih, b_hh, fc_w, fc_b, out);
}